// Round 6
// baseline (532.249 us; speedup 1.0000x reference)
//
#include <hip/hip_runtime.h>
#include <stdint.h>

// ---------------------------------------------------------------------------
// Self_postrans: pe(60ch) -> QKV -> softmax(sqrt(384) Q^T K) -> P V
// B=8, N=2048, D=384. fp32 I/O; internal fp16 MFMA (fp32 accum).
// K0: W fp32 -> fp16 hi/lo, padded 60->64 cols.
// K1: qkv, barrier-free: pe in regs (__sinf), W A-frags direct from global,
//     Q hi/lo (SC folded) + K fp16 [n][d], V fp16 [d][n] via wave-private LDS.
// K2: flash attn, barrier-free main loop: K/V frags direct from L2,
//     kv-split 2 per q-group (flash-decoding merge), 8 waves/CU.
// ---------------------------------------------------------------------------

typedef unsigned short u16;
typedef unsigned int   u32;
using h16x8 = __attribute__((ext_vector_type(8))) _Float16;
using f32x4 = __attribute__((ext_vector_type(4))) float;

#define MF16(a,b,c) __builtin_amdgcn_mfma_f32_16x16x32_f16((a),(b),(c),0,0,0)

__device__ __forceinline__ u16 f2h_u(float x) { union { _Float16 h; u16 u; } v; v.h = (_Float16)x; return v.u; }
__device__ __forceinline__ float h2f(u16 u)   { union { _Float16 h; u16 u; } v; v.u = u; return (float)v.h; }

union HU { h16x8 v; u16 e[8]; };

__device__ __forceinline__ float rmax16(float x) {
  x = fmaxf(x, __shfl_xor(x, 1, 16));
  x = fmaxf(x, __shfl_xor(x, 2, 16));
  x = fmaxf(x, __shfl_xor(x, 4, 16));
  x = fmaxf(x, __shfl_xor(x, 8, 16));
  return x;
}
__device__ __forceinline__ float rsum16(float x) {
  x += __shfl_xor(x, 1, 16);
  x += __shfl_xor(x, 2, 16);
  x += __shfl_xor(x, 4, 16);
  x += __shfl_xor(x, 8, 16);
  return x;
}

// ws byte offsets
#define QH_OFF 0u
#define QL_OFF 12582912u
#define KH_OFF 25165824u
#define VV_OFF 37748736u
#define WH_OFF 50331648u
#define WL_OFF 50479104u   // each W tensor: 3*384*64*2 = 147456 B

#define SC 19.595917942265423f  // sqrt(384)

// ---------------------------------------------------------------------------
// K0: convert W -> fp16 hi/lo, [mat][384][64] (cols 60..63 zero)
// ---------------------------------------------------------------------------
__global__ __launch_bounds__(256) void wconv_kernel(
    const float* __restrict__ Wq, const float* __restrict__ Wk,
    const float* __restrict__ Wv, u16* __restrict__ wh, u16* __restrict__ wl)
{
  int idx = blockIdx.x * 256 + threadIdx.x;
  if (idx >= 3 * 384 * 64) return;
  int mat = idx / 24576, rem = idx % 24576, d = rem >> 6, c = rem & 63;
  const float* W = (mat == 0) ? Wq : ((mat == 1) ? Wk : Wv);
  u16 hi = 0, lo = 0;
  if (c < 60) {
    float v = W[d * 60 + c];
    hi = f2h_u(v);
    lo = f2h_u(v - h2f(hi));
  }
  wh[idx] = hi; wl[idx] = lo;
}

// ---------------------------------------------------------------------------
// K1: qkv. grid 256 = (b = blk&7, nt = blk>>3), 256 thr (4 waves), 0 barriers.
// wave w owns d-strip [w*96, w*96+96) for all 3 mats; n-tile = nt*64..+64.
// ---------------------------------------------------------------------------
__global__ __launch_bounds__(256) void qkv_kernel(
    const float* __restrict__ pos,
    const float* __restrict__ bq, const float* __restrict__ bk,
    const float* __restrict__ bv,
    const u16* __restrict__ wh, const u16* __restrict__ wl,
    u16* __restrict__ qh, u16* __restrict__ ql,
    u16* __restrict__ kh, u16* __restrict__ vv)
{
  const int tid = threadIdx.x;
  const int b = blockIdx.x & 7, nt = blockIdx.x >> 3;
  const int w = tid >> 6, lane = tid & 63, q15 = lane & 15, quad = lane >> 4;

  __shared__ __align__(16) u16 sv[27648];  // 4 waves x 96 x 72 (wave-private V tiles)

  // ---- pe B-frags in registers: hi/lo fp16 ----
  h16x8 peh[2][4], pel[2][4];
#pragma unroll
  for (int nf = 0; nf < 4; ++nf) {
    const int ng = nt * 64 + nf * 16 + q15;
    float pv[3];
    pv[0] = pos[(b * 3 + 0) * 2048 + ng];
    pv[1] = pos[(b * 3 + 1) * 2048 + ng];
    pv[2] = pos[(b * 3 + 2) * 2048 + ng];
#pragma unroll
    for (int ks = 0; ks < 2; ++ks) {
      HU hh, hl;
#pragma unroll
      for (int j = 0; j < 8; ++j) {
        int c = ks * 32 + quad * 8 + j;
        u16 hi = 0, lo = 0;
        if (c < 60) {
          int co = (c >= 40) ? 2 : ((c >= 20) ? 1 : 0);
          int jj = c - co * 20;
          int f = (jj < 10) ? jj : jj - 10;
          float x = pv[co] * (float)(1 << f);
          float s = (jj < 10) ? __sinf(x) : __cosf(x);
          hi = f2h_u(s);
          lo = f2h_u(s - h2f(hi));
        }
        hh.e[j] = hi; hl.e[j] = lo;
      }
      peh[ks][nf] = hh.v; pel[ks][nf] = hl.v;
    }
  }

  for (int mat = 0; mat < 3; ++mat) {
    const float* bg = (mat == 0) ? bq : ((mat == 1) ? bk : bv);
    const u16* whm = wh + mat * 24576;
    const u16* wlm = wl + mat * 24576;

    f32x4 acc[6][4];
#pragma unroll
    for (int rf = 0; rf < 6; ++rf)
#pragma unroll
      for (int nf = 0; nf < 4; ++nf) acc[rf][nf] = (f32x4){0.f, 0.f, 0.f, 0.f};

#pragma unroll
    for (int ks = 0; ks < 2; ++ks) {
#pragma unroll
      for (int rf = 0; rf < 6; ++rf) {
        const int dr = w * 96 + rf * 16 + q15;
        h16x8 ah = *(const h16x8*)&whm[dr * 64 + ks * 32 + quad * 8];
        h16x8 al = *(const h16x8*)&wlm[dr * 64 + ks * 32 + quad * 8];
#pragma unroll
        for (int nf = 0; nf < 4; ++nf) {
          acc[rf][nf] = MF16(ah, peh[ks][nf], acc[rf][nf]);
          acc[rf][nf] = MF16(ah, pel[ks][nf], acc[rf][nf]);
          acc[rf][nf] = MF16(al, peh[ks][nf], acc[rf][nf]);
        }
      }
    }

    // bias + store (C-frag: d = dbase + r, n = nf*16+q15)
#pragma unroll
    for (int rf = 0; rf < 6; ++rf) {
      const int dbase = w * 96 + rf * 16 + quad * 4;
      float4 bi = *(const float4*)&bg[dbase];
#pragma unroll
      for (int nf = 0; nf < 4; ++nf) {
        float v0 = acc[rf][nf][0] + bi.x;
        float v1 = acc[rf][nf][1] + bi.y;
        float v2 = acc[rf][nf][2] + bi.z;
        float v3 = acc[rf][nf][3] + bi.w;
        const int n = nt * 64 + nf * 16 + q15;
        if (mat == 0) {
          v0 *= SC; v1 *= SC; v2 *= SC; v3 *= SC;
          u16 h0 = f2h_u(v0), h1 = f2h_u(v1), h2 = f2h_u(v2), h3 = f2h_u(v3);
          u16 g0 = f2h_u(v0 - h2f(h0)), g1 = f2h_u(v1 - h2f(h1));
          u16 g2 = f2h_u(v2 - h2f(h2)), g3 = f2h_u(v3 - h2f(h3));
          size_t off = ((size_t)(b * 2048 + n)) * 384 + dbase;
          uint2 pk0; pk0.x = (u32)h0 | ((u32)h1 << 16); pk0.y = (u32)h2 | ((u32)h3 << 16);
          uint2 pk1; pk1.x = (u32)g0 | ((u32)g1 << 16); pk1.y = (u32)g2 | ((u32)g3 << 16);
          *(uint2*)&qh[off] = pk0;
          *(uint2*)&ql[off] = pk1;
        } else if (mat == 1) {
          u16 h0 = f2h_u(v0), h1 = f2h_u(v1), h2 = f2h_u(v2), h3 = f2h_u(v3);
          size_t off = ((size_t)(b * 2048 + n)) * 384 + dbase;
          uint2 pk; pk.x = (u32)h0 | ((u32)h1 << 16); pk.y = (u32)h2 | ((u32)h3 << 16);
          *(uint2*)&kh[off] = pk;
        } else {
          const int dl = rf * 16 + quad * 4;   // wave-local d
          sv[w * 6912 + (dl + 0) * 72 + nf * 16 + q15] = f2h_u(v0);
          sv[w * 6912 + (dl + 1) * 72 + nf * 16 + q15] = f2h_u(v1);
          sv[w * 6912 + (dl + 2) * 72 + nf * 16 + q15] = f2h_u(v2);
          sv[w * 6912 + (dl + 3) * 72 + nf * 16 + q15] = f2h_u(v3);
        }
      }
    }

    if (mat == 2) {
      // wave-private transpose copy-out (same wave wrote sv -> lgkmcnt only)
#pragma unroll
      for (int t = 0; t < 12; ++t) {
        int idx = t * 64 + lane;
        int dl = idx >> 3, k = idx & 7;
        *(uint4*)&vv[((size_t)(b * 384 + w * 96 + dl)) * 2048 + nt * 64 + k * 8] =
            *(const uint4*)&sv[w * 6912 + dl * 72 + k * 8];
      }
    }
  }
}

// ---------------------------------------------------------------------------
// K2: flash attn. grid 512 = (b = blk&7, qt = blk>>3), 256 thr (4 waves).
// wave: g = w&1 (q-group: qt*32 + g*16, 16 rows), hv = w>>1 (kv half).
// Barrier-free main loop; K/V frags direct from global (L2); single merge
// barrier at the end (flash-decoding combine).
// ---------------------------------------------------------------------------
__global__ __launch_bounds__(256, 2) void attn_kernel(
    const u16* __restrict__ qhp, const u16* __restrict__ qlp,
    const u16* __restrict__ khp, const u16* __restrict__ vvp,
    float* __restrict__ outp)
{
  const int tid = threadIdx.x;
  const int b = blockIdx.x & 7, qt = blockIdx.x >> 3;
  const int w = tid >> 6, lane = tid & 63, q15 = lane & 15, quad = lane >> 4;
  const int g = w & 1, hv = w >> 1;

  __shared__ __align__(16) u16 sp[4 * 640];    // P: per-wave 16 x 40
  __shared__ __align__(16) float ob[2 * 16 * 388];  // merge O (49664 B)
  __shared__ float sml[2][2][16];              // m, l from hv=1 waves

  // Q frags (fp16 hi/lo, SC folded)
  h16x8 qfh[12], qfl[12];
  {
    const size_t qr = ((size_t)(b * 2048 + qt * 32 + g * 16 + q15)) * 384;
#pragma unroll
    for (int ks = 0; ks < 12; ++ks) {
      qfh[ks] = *(const h16x8*)&qhp[qr + ks * 32 + quad * 8];
      qfl[ks] = *(const h16x8*)&qlp[qr + ks * 32 + quad * 8];
    }
  }

  f32x4 o[24];
#pragma unroll
  for (int cf = 0; cf < 24; ++cf) o[cf] = (f32x4){0.f, 0.f, 0.f, 0.f};
  float mo[4], ll[4];
#pragma unroll
  for (int r = 0; r < 4; ++r) { mo[r] = -1e30f; ll[r] = 0.f; }

  for (int t = 0; t < 32; ++t) {
    const int mt = hv * 32 + t;
    const size_t kb = ((size_t)(b * 2048 + mt * 32)) * 384;

    // ---- S: K frags direct from L2 ----
    f32x4 s0h = {0.f,0.f,0.f,0.f}, s0l = {0.f,0.f,0.f,0.f};
    f32x4 s1h = {0.f,0.f,0.f,0.f}, s1l = {0.f,0.f,0.f,0.f};
#pragma unroll
    for (int ks = 0; ks < 12; ++ks) {
      h16x8 b0 = *(const h16x8*)&khp[kb + (size_t)q15 * 384 + ks * 32 + quad * 8];
      h16x8 b1 = *(const h16x8*)&khp[kb + (size_t)(16 + q15) * 384 + ks * 32 + quad * 8];
      s0h = MF16(qfh[ks], b0, s0h);
      s0l = MF16(qfl[ks], b0, s0l);
      s1h = MF16(qfh[ks], b1, s1h);
      s1l = MF16(qfl[ks], b1, s1l);
    }
    f32x4 sa0 = s0h + s0l, sa1 = s1h + s1l;

    // ---- online softmax (regs + shfl over q15) ----
    float al_[4], p0[4], p1[4];
#pragma unroll
    for (int r = 0; r < 4; ++r) {
      float mx = rmax16(fmaxf(sa0[r], sa1[r]));
      float mn = fmaxf(mo[r], mx);
      al_[r] = __expf(mo[r] - mn);
      mo[r] = mn;
      p0[r] = __expf(sa0[r] - mn);
      p1[r] = __expf(sa1[r] - mn);
      ll[r] = ll[r] * al_[r] + rsum16(p0[r] + p1[r]);
    }
    // P -> wave-private LDS (C-layout write, A-layout read; same wave)
#pragma unroll
    for (int r = 0; r < 4; ++r) {
      sp[w * 640 + (quad * 4 + r) * 40 +      q15] = f2h_u(p0[r]);
      sp[w * 640 + (quad * 4 + r) * 40 + 16 + q15] = f2h_u(p1[r]);
    }
#pragma unroll
    for (int cf = 0; cf < 24; ++cf)
#pragma unroll
      for (int r = 0; r < 4; ++r) o[cf][r] *= al_[r];

    // ---- PV: V frags direct from L2 ----
    h16x8 pa = *(const h16x8*)&sp[w * 640 + q15 * 40 + quad * 8];
    const size_t vb0 = (size_t)b * 384 * 2048 + mt * 32 + quad * 8;
#pragma unroll
    for (int cf = 0; cf < 24; ++cf) {
      h16x8 vb = *(const h16x8*)&vvp[vb0 + (size_t)(cf * 16 + q15) * 2048];
      o[cf] = MF16(pa, vb, o[cf]);
    }
  }

  // ---- merge the two kv-halves of each q-group ----
  if (hv == 1) {
#pragma unroll
    for (int cf = 0; cf < 24; ++cf)
#pragma unroll
      for (int r = 0; r < 4; ++r)
        ob[g * 6208 + (quad * 4 + r) * 388 + cf * 16 + q15] = o[cf][r];
    if (q15 == 0)
#pragma unroll
      for (int r = 0; r < 4; ++r) {
        sml[g][0][quad * 4 + r] = mo[r];
        sml[g][1][quad * 4 + r] = ll[r];
      }
  }
  __syncthreads();
  if (hv == 0) {
    float w1[4], w2[4];
#pragma unroll
    for (int r = 0; r < 4; ++r) {
      float m2 = sml[g][0][quad * 4 + r], l2 = sml[g][1][quad * 4 + r];
      float ms = fmaxf(mo[r], m2);
      float e1 = __expf(mo[r] - ms), e2 = __expf(m2 - ms);
      float li = 1.0f / (ll[r] * e1 + l2 * e2);
      w1[r] = e1 * li; w2[r] = e2 * li;
    }
#pragma unroll
    for (int cf = 0; cf < 24; ++cf) {
      float4 st;
      st.x = o[cf][0] * w1[0] + ob[g * 6208 + (quad * 4 + 0) * 388 + cf * 16 + q15] * w2[0];
      st.y = o[cf][1] * w1[1] + ob[g * 6208 + (quad * 4 + 1) * 388 + cf * 16 + q15] * w2[1];
      st.z = o[cf][2] * w1[2] + ob[g * 6208 + (quad * 4 + 2) * 388 + cf * 16 + q15] * w2[2];
      st.w = o[cf][3] * w1[3] + ob[g * 6208 + (quad * 4 + 3) * 388 + cf * 16 + q15] * w2[3];
      // out[b][d = cf*16+q15][n = qt*32 + g*16 + quad*4 + r]
      *(float4*)&outp[((size_t)(b * 384 + cf * 16 + q15)) * 2048 + qt * 32 + g * 16 + quad * 4] = st;
    }
  }
}

extern "C" void kernel_launch(void* const* d_in, const int* in_sizes, int n_in,
                              void* d_out, int out_size, void* d_ws, size_t ws_size,
                              hipStream_t stream) {
  const float* pos = (const float*)d_in[0];
  const float* Wq  = (const float*)d_in[1];
  const float* bq  = (const float*)d_in[2];
  const float* Wk  = (const float*)d_in[3];
  const float* bk  = (const float*)d_in[4];
  const float* Wv  = (const float*)d_in[5];
  const float* bv  = (const float*)d_in[6];

  char* ws = (char*)d_ws;
  u16* qh = (u16*)(ws + QH_OFF);
  u16* ql = (u16*)(ws + QL_OFF);
  u16* kh = (u16*)(ws + KH_OFF);
  u16* vv = (u16*)(ws + VV_OFF);
  u16* wh = (u16*)(ws + WH_OFF);
  u16* wl = (u16*)(ws + WL_OFF);

  wconv_kernel<<<288, 256, 0, stream>>>(Wq, Wk, Wv, wh, wl);
  qkv_kernel<<<256, 256, 0, stream>>>(pos, bq, bk, bv, wh, wl, qh, ql, kh, vv);
  attn_kernel<<<512, 256, 0, stream>>>(qh, ql, kh, vv, (float*)d_out);
}